// Round 10
// baseline (85.835 us; speedup 1.0000x reference)
//
#include <hip/hip_runtime.h>
#include <math.h>

// query [4,32,64,64] f32, key [4,32,64,192] f32
// ROUND 10 = MEASUREMENT BUILD: R8 structure, inner loop executed REP=16x
// (combined via fmaxf -> bitwise-identical result, output unchanged).
// Purpose: make A's loop cost visible in dur_us (and its counters in top-5).
#define B 4
#define C 32
#define H 64
#define WQ 64
#define WK 192
#define NP 129                    // P = 192 - 64 + 1
#define ROWS (C * H)              // 2048 rows per batch
#define ELEMS (ROWS * WQ)         // 131072 elements per (b,p)
#define GB 256                    // blocks per batch
#define WPB 4                     // waves per block
#define RPW 2                     // rows per wave
#define PSTRIDE 132               // padded partial-row stride (floats)
#define KPAD 200                  // padded LDS k-row stride
#define REP 16                    // inner-loop repetition factor (measurement)

__global__ __launch_bounds__(256, 4) void patch_l1_partial(const float* __restrict__ query,
                                                           const float* __restrict__ key,
                                                           float* __restrict__ part) {
    __shared__ __align__(16) float kbuf[WPB][RPW][KPAD];  // 2 k-rows per wave
    __shared__ float red[WPB][130];                       // padded for float2 writes

    const int bid  = blockIdx.x;
    const int b    = bid >> 8;           // / GB
    const int g    = bid & (GB - 1);
    const int t    = threadIdx.x;
    const int wv   = t >> 6;
    const int lane = t & 63;
    const int slot = __builtin_amdgcn_readfirstlane(g * WPB + (t >> 6));
    const int r0   = slot * RPW;         // this wave's two rows

    const float* __restrict__ qb = query + (size_t)b * ELEMS;
    const float* __restrict__ kb = key   + (size_t)b * ROWS * WK + (size_t)r0 * WK;

    // stage both k-rows into wave-private LDS (lane<48: one float4 per row)
    if (lane < 48) {
        const float4 v0 = *reinterpret_cast<const float4*>(kb + lane * 4);
        const float4 v1 = *reinterpret_cast<const float4*>(kb + WK + lane * 4);
        *reinterpret_cast<float4*>(&kbuf[wv][0][lane * 4]) = v0;
        *reinterpret_cast<float4*>(&kbuf[wv][1][lane * 4]) = v1;
    }
    // per-lane q values for the p=128 terms
    const float q0l = qb[(size_t)r0 * WQ + lane];
    const float q1l = qb[(size_t)(r0 + 1) * WQ + lane];

    float acc_a = 0.f, acc_b = 0.f, acc2 = 0.f;

    #pragma unroll
    for (int rr = 0; rr < RPW; ++rr) {
        // hoist the row's q: uniform pointer + compile-time offsets
        const float* __restrict__ qr = qb + (size_t)(r0 + rr) * WQ;
        float qs[64];
        #pragma unroll
        for (int s4 = 0; s4 < 16; ++s4) {
            const float4 qv = *reinterpret_cast<const float4*>(qr + s4 * 4);
            qs[s4 * 4 + 0] = qv.x; qs[s4 * 4 + 1] = qv.y;
            qs[s4 * 4 + 2] = qv.z; qs[s4 * 4 + 3] = qv.w;
        }

        const float* __restrict__ k0 = &kbuf[wv][rr][0];

        float row_a = 0.f, row_b = 0.f;   // all reps identical; fmax keeps exact value

        #pragma unroll 1
        for (int rep = 0; rep < REP; ++rep) {
            asm volatile("" ::: "memory");   // forbid CSE/LICM across reps
            float aa0 = 0.f, aa1 = 0.f, bb0 = 0.f, bb1 = 0.f;

            #pragma unroll
            for (int si = 0; si < 16; ++si) {
                const int s = si * 4;
                const float2 ka = *reinterpret_cast<const float2*>(&k0[2 * lane + s]);
                const float2 kc = *reinterpret_cast<const float2*>(&k0[2 * lane + s + 2]);
                aa0 += fabsf(ka.x - qs[s]);                    // p=2l,   w=s
                if (si > 0) bb0 += fabsf(ka.x - qs[s - 1]);    // p=2l+1, w=s-1
                aa1 += fabsf(ka.y - qs[s + 1]);                // p=2l,   w=s+1
                bb1 += fabsf(ka.y - qs[s]);                    // p=2l+1, w=s
                aa0 += fabsf(kc.x - qs[s + 2]);                // p=2l,   w=s+2
                bb0 += fabsf(kc.x - qs[s + 1]);                // p=2l+1, w=s+1
                aa1 += fabsf(kc.y - qs[s + 3]);                // p=2l,   w=s+3
                bb1 += fabsf(kc.y - qs[s + 2]);                // p=2l+1, w=s+2
            }
            bb0 += fabsf(k0[2 * lane + 64] - qs[63]);          // tail: p=2l+1, w=63

            row_a = fmaxf(row_a, aa0 + aa1);
            row_b = fmaxf(row_b, bb0 + bb1);
        }

        acc_a += row_a;
        acc_b += row_b;
        acc2  += fabsf(k0[128 + lane] - (rr ? q1l : q0l));     // p=128, w=lane
    }

    // wave-reduce the p=128 accumulator across 64 lanes
    #pragma unroll
    for (int m = 32; m; m >>= 1) acc2 += __shfl_xor(acc2, m, 64);

    *reinterpret_cast<float2*>(&red[wv][2 * lane]) = make_float2(acc_a, acc_b);
    if (lane == 0) red[wv][128] = acc2;
    __syncthreads();

    if (t < NP)
        part[(size_t)bid * PSTRIDE + t] = red[0][t] + red[1][t] + red[2][t] + red[3][t];
}

// Kernel B (R8-identical): one 1024-thread block per batch.
__global__ __launch_bounds__(1024) void patch_l1_final(const float* __restrict__ part,
                                                       float* __restrict__ out) {
    const int b    = blockIdx.x;
    const int t    = threadIdx.x;
    const int wv   = t >> 6;       // 0..15
    const int lane = t & 63;

    float acc0 = 0.f, acc1 = 0.f, acc2 = 0.f;
    #pragma unroll 4
    for (int g = wv; g < GB; g += 16) {
        const float* __restrict__ src = part + ((size_t)b * GB + g) * PSTRIDE;
        acc0 += src[lane];
        acc1 += src[64 + lane];
        if (lane == 0) acc2 += src[128];
    }

    __shared__ float red[16][NP];
    red[wv][lane]      = acc0;
    red[wv][64 + lane] = acc1;
    if (lane == 0) red[wv][128] = acc2;
    __syncthreads();

    float y = INFINITY;
    int idx = NP;
    if (t < NP) {
        float s = 0.f;
        #pragma unroll
        for (int w = 0; w < 16; ++w) s += red[w][t];
        y = s * (1.0f / (float)ELEMS);
        idx = t;
    }

    __shared__ float sy[256];
    __shared__ int   si[256];
    if (t < 256) { sy[t] = y; si[t] = idx; }
    __syncthreads();
    #pragma unroll
    for (int s = 128; s > 0; s >>= 1) {
        if (t < s) {
            const float yo = sy[t + s];
            const int   io = si[t + s];
            if (yo < sy[t] || (yo == sy[t] && io < si[t])) {
                sy[t] = yo;
                si[t] = io;
            }
        }
        __syncthreads();
    }

    if (t == 0) {
        out[b]     = (float)si[0];
        out[5 + b] = sy[0];
        if (b == 0) out[4] = (float)NP;
    }
}

extern "C" void kernel_launch(void* const* d_in, const int* in_sizes, int n_in,
                              void* d_out, int out_size, void* d_ws, size_t ws_size,
                              hipStream_t stream) {
    const float* query = (const float*)d_in[0];
    const float* key   = (const float*)d_in[1];
    float* out  = (float*)d_out;
    float* part = (float*)d_ws;   // B*GB*PSTRIDE floats = 540 KB, block-owned

    patch_l1_partial<<<B * GB, 256, 0, stream>>>(query, key, part);
    patch_l1_final<<<B, 1024, 0, stream>>>(part, out);
}

// Round 11
// 18.514 us; speedup vs baseline: 4.6362x; 4.6362x over previous
//
#include <hip/hip_runtime.h>
#include <math.h>

// query [4,32,64,64] f32, key [4,32,64,192] f32
#define B 4
#define C 32
#define H 64
#define WQ 64
#define WK 192
#define NP 129                    // P = 192 - 64 + 1
#define ROWS (C * H)              // 2048 rows per batch
#define ELEMS (ROWS * WQ)         // 131072 elements per (b,p)
#define GB 256                    // blocks per batch
#define WPB 4                     // waves per block
#define RPW 2                     // rows per wave
#define KPAD 200                  // padded LDS k-row stride

// Kernel A (R8-identical loop): lane l owns shifts p=2l, p=2l+1. Rows processed
// sequentially; row's 64 q-values hoisted via uniform pointer (SGPRs). Inner
// loop pure {ds_read_b64 + VALU}, 4 accumulator chains.
// CHANGE vs R8: partials stored TRANSPOSED part[(b*NP+p)*GB+g] so kernel B can
// use vectorized coalesced loads.
__global__ __launch_bounds__(256, 4) void patch_l1_partial(const float* __restrict__ query,
                                                           const float* __restrict__ key,
                                                           float* __restrict__ part) {
    __shared__ __align__(16) float kbuf[WPB][RPW][KPAD];  // 2 k-rows per wave
    __shared__ float red[WPB][130];                       // padded for float2 writes

    const int bid  = blockIdx.x;
    const int b    = bid >> 8;           // / GB
    const int g    = bid & (GB - 1);
    const int t    = threadIdx.x;
    const int wv   = t >> 6;
    const int lane = t & 63;
    const int slot = __builtin_amdgcn_readfirstlane(g * WPB + (t >> 6));
    const int r0   = slot * RPW;         // this wave's two rows

    const float* __restrict__ qb = query + (size_t)b * ELEMS;
    const float* __restrict__ kb = key   + (size_t)b * ROWS * WK + (size_t)r0 * WK;

    // stage both k-rows into wave-private LDS (lane<48: one float4 per row)
    if (lane < 48) {
        const float4 v0 = *reinterpret_cast<const float4*>(kb + lane * 4);
        const float4 v1 = *reinterpret_cast<const float4*>(kb + WK + lane * 4);
        *reinterpret_cast<float4*>(&kbuf[wv][0][lane * 4]) = v0;
        *reinterpret_cast<float4*>(&kbuf[wv][1][lane * 4]) = v1;
    }
    // per-lane q values for the p=128 terms
    const float q0l = qb[(size_t)r0 * WQ + lane];
    const float q1l = qb[(size_t)(r0 + 1) * WQ + lane];

    float acc_a = 0.f, acc_b = 0.f, acc2 = 0.f;

    #pragma unroll
    for (int rr = 0; rr < RPW; ++rr) {
        // hoist the row's q: uniform pointer + compile-time offsets
        const float* __restrict__ qr = qb + (size_t)(r0 + rr) * WQ;
        float qs[64];
        #pragma unroll
        for (int s4 = 0; s4 < 16; ++s4) {
            const float4 qv = *reinterpret_cast<const float4*>(qr + s4 * 4);
            qs[s4 * 4 + 0] = qv.x; qs[s4 * 4 + 1] = qv.y;
            qs[s4 * 4 + 2] = qv.z; qs[s4 * 4 + 3] = qv.w;
        }

        const float* __restrict__ k0 = &kbuf[wv][rr][0];
        float aa0 = 0.f, aa1 = 0.f, bb0 = 0.f, bb1 = 0.f;

        #pragma unroll
        for (int si = 0; si < 16; ++si) {
            const int s = si * 4;
            const float2 ka = *reinterpret_cast<const float2*>(&k0[2 * lane + s]);
            const float2 kc = *reinterpret_cast<const float2*>(&k0[2 * lane + s + 2]);
            aa0 += fabsf(ka.x - qs[s]);                    // p=2l,   w=s
            if (si > 0) bb0 += fabsf(ka.x - qs[s - 1]);    // p=2l+1, w=s-1
            aa1 += fabsf(ka.y - qs[s + 1]);                // p=2l,   w=s+1
            bb1 += fabsf(ka.y - qs[s]);                    // p=2l+1, w=s
            aa0 += fabsf(kc.x - qs[s + 2]);                // p=2l,   w=s+2
            bb0 += fabsf(kc.x - qs[s + 1]);                // p=2l+1, w=s+1
            aa1 += fabsf(kc.y - qs[s + 3]);                // p=2l,   w=s+3
            bb1 += fabsf(kc.y - qs[s + 2]);                // p=2l+1, w=s+2
        }
        bb0 += fabsf(k0[2 * lane + 64] - qs[63]);          // tail: p=2l+1, w=63

        acc_a += aa0 + aa1;
        acc_b += bb0 + bb1;
        acc2  += fabsf(k0[128 + lane] - (rr ? q1l : q0l)); // p=128, w=lane
    }

    // wave-reduce the p=128 accumulator across 64 lanes
    #pragma unroll
    for (int m = 32; m; m >>= 1) acc2 += __shfl_xor(acc2, m, 64);

    *reinterpret_cast<float2*>(&red[wv][2 * lane]) = make_float2(acc_a, acc_b);
    if (lane == 0) red[wv][128] = acc2;
    __syncthreads();

    if (t < NP) {
        const float v = red[0][t] + red[1][t] + red[2][t] + red[3][t];
        part[((size_t)b * NP + t) * GB + g] = v;   // transposed for kernel B
    }
}

// Kernel B (new): 4 blocks x 1024 threads. Thread t owns (p = t>>3, sub = t&7):
// 8 INDEPENDENT float4 loads (32 consecutive g-partials) -> all latency
// overlapped; 8-lane shuffle reduce -> y[p]. Wave 0 also reduces p=128
// (64 lanes x one float4). Then first-index min/argmin tree over 129.
__global__ __launch_bounds__(1024) void patch_l1_final(const float* __restrict__ part,
                                                       float* __restrict__ out) {
    const int b   = blockIdx.x;
    const int t   = threadIdx.x;
    const int p   = t >> 3;        // 0..127
    const int sub = t & 7;

    const float inv = 1.0f / (float)ELEMS;

    // main: p in [0,128)
    const float* __restrict__ src = part + ((size_t)b * NP + p) * GB + sub * 32;
    float4 s4 = make_float4(0.f, 0.f, 0.f, 0.f);
    #pragma unroll
    for (int j = 0; j < 8; ++j) {
        const float4 v = *reinterpret_cast<const float4*>(src + j * 4);
        s4.x += v.x; s4.y += v.y; s4.z += v.z; s4.w += v.w;
    }
    float v = (s4.x + s4.y) + (s4.z + s4.w);
    v += __shfl_xor(v, 1, 64);
    v += __shfl_xor(v, 2, 64);
    v += __shfl_xor(v, 4, 64);

    // p = 128: wave 0 (threads 0..63), one float4 each
    float v128 = 0.f;
    if (t < 64) {
        const float4 w4 = *reinterpret_cast<const float4*>(part + ((size_t)b * NP + 128) * GB + t * 4);
        v128 = (w4.x + w4.y) + (w4.z + w4.w);
        #pragma unroll
        for (int m = 32; m; m >>= 1) v128 += __shfl_xor(v128, m, 64);
    }

    __shared__ float red[NP];
    if (sub == 0) red[p] = v * inv;
    if (t == 0)   red[128] = v128 * inv;
    __syncthreads();

    // argmin over 129 by the first 256 threads (first-index tie-break)
    __shared__ float sy[256];
    __shared__ int   si[256];
    if (t < 256) {
        float y = INFINITY;
        int idx = NP;
        if (t < NP) { y = red[t]; idx = t; }
        sy[t] = y;
        si[t] = idx;
    }
    __syncthreads();
    #pragma unroll
    for (int s = 128; s > 0; s >>= 1) {
        if (t < s) {
            const float yo = sy[t + s];
            const int   io = si[t + s];
            if (yo < sy[t] || (yo == sy[t] && io < si[t])) {
                sy[t] = yo;
                si[t] = io;
            }
        }
        __syncthreads();
    }

    if (t == 0) {
        out[b]     = (float)si[0];
        out[5 + b] = sy[0];
        if (b == 0) out[4] = (float)NP;
    }
}

extern "C" void kernel_launch(void* const* d_in, const int* in_sizes, int n_in,
                              void* d_out, int out_size, void* d_ws, size_t ws_size,
                              hipStream_t stream) {
    const float* query = (const float*)d_in[0];
    const float* key   = (const float*)d_in[1];
    float* out  = (float*)d_out;
    float* part = (float*)d_ws;   // B*NP*GB floats = 528 KB, block-owned

    patch_l1_partial<<<B * GB, 256, 0, stream>>>(query, key, part);
    patch_l1_final<<<B, 1024, 0, stream>>>(part, out);
}